// Round 8
// baseline (65.349 us; speedup 1.0000x reference)
//
#include <hip/hip_runtime.h>
#include <math.h>

typedef __attribute__((ext_vector_type(8))) short short8;
typedef __attribute__((ext_vector_type(4))) float f32x4;
using half8 = __attribute__((ext_vector_type(8))) _Float16;

constexpr int kN = 64;     // nodes per batch
constexpr int kF = 13;     // features
constexpr int kD = 128;    // hidden dim
constexpr int kSelf = 6;
constexpr float kTemp = 0.08838834764831845f;   // 1/sqrt(128)
constexpr float kLoScale = 4096.f;              // weight-lo plane scale (avoids f16 denormals)
constexpr float kLoInv   = 1.0f / 4096.f;

// ws layout (ushort element offsets). Weight planes FRAGMENT-PACKED in lane
// order: chunk = 512 ushorts (64 lanes x 8 f16 = 1KB); wave load = base+lane*16B.
// Q/K planes (split f16 hi/lo): 32 chunks, chunk c=(dtile<<2)|ks, lane l=(lg<<4)|lc:
//   W[dtile*16+lc][ks*32+lg*8+e]
// phi planes (hi only): 8 chunks (nt): P[nt*16+lc][lg*8+e], k>=13 zero-padded
// f32 region at ushort offset WS_F32:
//   [0..127]  fvec  = v_w^T @ final_w[:128]
//   [128..133] gvec = phi1_w^T @ final_w[128:]
//   [134]     const = final_b + final_w[:128].v_b + final_w[128:].phi1_b
constexpr int WS_QH  = 0;
constexpr int WS_QL  = 16384;
constexpr int WS_KH  = 32768;
constexpr int WS_KL  = 49152;
constexpr int WS_P3  = 65536;
constexpr int WS_P2  = 69632;
constexpr int WS_F32 = 73728;   // total ws: 147456 + 540 bytes

__device__ __forceinline__ ushort f16h(float v) {
  _Float16 h = (_Float16)v;
  return __builtin_bit_cast(unsigned short, h);
}
__device__ __forceinline__ float f16f(ushort b) {
  return (float)__builtin_bit_cast(_Float16, b);
}
__device__ __forceinline__ half8 ld_h8(const ushort* p) {
  return __builtin_bit_cast(half8, *(const short8*)p);
}
#define MFMA16(a, b, c) __builtin_amdgcn_mfma_f32_16x16x32_f16((a), (b), (c), 0, 0, 0)

__global__ __launch_bounds__(256) void prep_kernel(
    const float* __restrict__ q_w, const float* __restrict__ k_w,
    const float* __restrict__ p3w, const float* __restrict__ p2w,
    const float* __restrict__ v_w, const float* __restrict__ phi1_w,
    const float* __restrict__ phi1_b, const float* __restrict__ v_b,
    const float* __restrict__ final_w, const float* __restrict__ final_b,
    ushort* __restrict__ ws)
{
  const int i = blockIdx.x * 256 + threadIdx.x;
  if (i < 32768) {            // Q / K split fragment planes
    const int j = i & 16383;
    const bool isQ = i < 16384;
    const int c  = j >> 9;
    const int l  = (j >> 3) & 63;
    const int e  = j & 7;
    const int lc = l & 15, lg = l >> 4;
    const int drow = (c >> 2) * 16 + lc;
    const int ks   = c & 3;
    const float v = (isQ ? q_w : k_w)[drow * kD + ks * 32 + lg * 8 + e];
    const ushort h  = f16h(v);
    const ushort lo = f16h((v - f16f(h)) * kLoScale);
    if (isQ) { ws[WS_QH + j] = h; ws[WS_QL + j] = lo; }
    else     { ws[WS_KH + j] = h; ws[WS_KL + j] = lo; }
  } else if (i < 40960) {     // phi3 / phi2 hi-only fragment planes
    const int j = (i - 32768) & 4095;
    const bool is3 = i < 36864;
    const int nt = j >> 9;
    const int l  = (j >> 3) & 63;
    const int e  = j & 7;
    const int lc = l & 15, lg = l >> 4;
    const int dcol = nt * 16 + lc;
    const int k    = lg * 8 + e;
    const float v = (k < kF) ? (is3 ? p3w : p2w)[dcol * kF + k] : 0.f;
    ws[(is3 ? WS_P3 : WS_P2) + j] = f16h(v);
  } else if (i < 41088) {     // fvec[j] = sum_d final_w[d] * v_w[d][j]
    const int j = i - 40960;
    float acc = 0.f;
    for (int d2 = 0; d2 < kD; ++d2) acc = fmaf(final_w[d2], v_w[d2 * kD + j], acc);
    ((float*)(ws + WS_F32))[j] = acc;
  } else if (i < 41094) {     // gvec[j] = sum_d final_w[128+d] * phi1_w[d][j]
    const int j = i - 41088;
    float acc = 0.f;
    for (int d2 = 0; d2 < kD; ++d2) acc = fmaf(final_w[kD + d2], phi1_w[d2 * kSelf + j], acc);
    ((float*)(ws + WS_F32))[128 + j] = acc;
  } else if (i == 41094) {    // const
    float acc = final_b[0];
    for (int d2 = 0; d2 < kD; ++d2) acc = fmaf(final_w[d2], v_b[d2], acc);
    for (int d2 = 0; d2 < kD; ++d2) acc = fmaf(final_w[kD + d2], phi1_b[d2], acc);
    ((float*)(ws + WS_F32))[134] = acc;
  }
}

// One block (256 threads = 4 waves) per batch element. TWO barriers:
//   B: phi3 (h3 -> LDS) + phi2-t (t[n] -> LDS)   | barrier
//   C: Q pass (qsum in-lane) + K pass (spart)    | barrier
//   D: wave 0: softmax + out = sum w[m]*t[m] + gvec.s0 + const
__global__ __launch_bounds__(256) void value_net_kernel(
    const float* __restrict__ state,
    const float* __restrict__ phi2_b, const float* __restrict__ phi3_b,
    const float* __restrict__ q_b,    const float* __restrict__ k_b,
    const ushort* __restrict__ wsc,
    float* __restrict__ out)
{
  const int b    = blockIdx.x;
  const int tid  = threadIdx.x;
  const int lane = tid & 63;
  const int wave = tid >> 6;
  const int lc   = lane & 15;   // fragment col / row-in-tile
  const int lg   = lane >> 4;   // fragment k-octet / row-group

  __shared__ __align__(16) ushort h3[kN * kD];    // f16 bits, XOR-swizzled
  __shared__ float spart[4][kN];
  __shared__ float t_lds[kN];

  // ---- A-fragment of state (f16) straight from global (no staging phase) ----
  // A[row=lc][k=lg*8+e]; rows = this wave's 16 nodes; k>=13 zero.
  short8 a3s = {0, 0, 0, 0, 0, 0, 0, 0};
  if (lg < 2) {
    const float* rowp = state + (size_t)b * (kN * kF) + (wave * 16 + lc) * kF + lg * 8;
#pragma unroll
    for (int i = 0; i < 8; ++i) {
      const int k = lg * 8 + i;
      float x = 0.f;
      if (k < kF) x = rowp[i];
      a3s[i] = (short)f16h(x);
    }
  }
  const half8 a3 = __builtin_bit_cast(half8, a3s);

  // ---- phase B1: phi3 via MFMA (hi-only): h3 -> f16 LDS, XOR-swizzled ----
#pragma unroll
  for (int nt = 0; nt < 8; ++nt) {
    const int dcol = nt * 16 + lc;
    half8 bh = ld_h8(&wsc[WS_P3 + nt * 512 + lane * 8]);
    f32x4 aH = {0.f, 0.f, 0.f, 0.f};
    aH = MFMA16(a3, bh, aH);
    const float bias = phi3_b[dcol];
#pragma unroll
    for (int r = 0; r < 4; ++r) {
      const int nw = wave * 16 + lg * 4 + r;
      float v = fmaxf(aH[r] + bias, 0.f);
      h3[(nw * kD + dcol) ^ ((nw & 7) << 3)] = f16h(v);
    }
  }

  // ---- phase B2: phi2-t: t[n] = fvec . relu(h2[n] + b2)  (pre-softmax!) ----
  {
    const float* fws = (const float*)(wsc + WS_F32);
    float tp[4] = {0.f, 0.f, 0.f, 0.f};
#pragma unroll
    for (int nt = 0; nt < 8; ++nt) {
      const int dcol = nt * 16 + lc;
      half8 bh = ld_h8(&wsc[WS_P2 + nt * 512 + lane * 8]);
      f32x4 aH = {0.f, 0.f, 0.f, 0.f};
      aH = MFMA16(a3, bh, aH);
      const float b2 = phi2_b[dcol];
      const float fv = fws[dcol];
#pragma unroll
      for (int r = 0; r < 4; ++r)
        tp[r] = fmaf(fv, fmaxf(aH[r] + b2, 0.f), tp[r]);
    }
#pragma unroll
    for (int r = 0; r < 4; ++r) {
      tp[r] += __shfl_xor(tp[r], 1, 64);
      tp[r] += __shfl_xor(tp[r], 2, 64);
      tp[r] += __shfl_xor(tp[r], 4, 64);
      tp[r] += __shfl_xor(tp[r], 8, 64);
    }
    if (lc == 0) {
#pragma unroll
      for (int r = 0; r < 4; ++r) t_lds[wave * 16 + lg * 4 + r] = tp[r];
    }
  }
  __syncthreads();  // h3 + t ready

  const int dbase = wave * 32;

  // ---- phase C1: Q pass (split f16): qsum[d] = sum_n relu(Q[n][d]+qb) ----
  float qs[2] = {0.f, 0.f};
  {
    const float qbv[2] = {q_b[dbase + lc], q_b[dbase + 16 + lc]};
    half8 bqh[2][4], bql[2][4];
#pragma unroll
    for (int dtl = 0; dtl < 2; ++dtl) {
      const int cb = (wave * 2 + dtl) * 4;
#pragma unroll
      for (int ks = 0; ks < 4; ++ks) {
        bqh[dtl][ks] = ld_h8(&wsc[WS_QH + (cb + ks) * 512 + lane * 8]);
        bql[dtl][ks] = ld_h8(&wsc[WS_QL + (cb + ks) * 512 + lane * 8]);
      }
    }
#pragma unroll
    for (int nt = 0; nt < 4; ++nt) {
      const int row = nt * 16 + lc;
      const int rb  = row * kD;
      const int swz = (row & 7) << 3;
      half8 ah[4];
#pragma unroll
      for (int ks = 0; ks < 4; ++ks)
        ah[ks] = ld_h8(&h3[(rb + ks * 32 + lg * 8) ^ swz]);
#pragma unroll
      for (int dtl = 0; dtl < 2; ++dtl) {
        f32x4 aH = {0.f, 0.f, 0.f, 0.f}, aL = {0.f, 0.f, 0.f, 0.f};
#pragma unroll
        for (int ks = 0; ks < 4; ++ks) {
          aH = MFMA16(ah[ks], bqh[dtl][ks], aH);
          aL = MFMA16(ah[ks], bql[dtl][ks], aL);
        }
#pragma unroll
        for (int r = 0; r < 4; ++r)
          qs[dtl] += fmaxf(fmaf(kLoInv, aL[r], aH[r]) + qbv[dtl], 0.f);
      }
    }
  }
#pragma unroll
  for (int dtl = 0; dtl < 2; ++dtl) {
    qs[dtl] += __shfl_xor(qs[dtl], 16, 64);
    qs[dtl] += __shfl_xor(qs[dtl], 32, 64);
  }

  // ---- phase C2: K pass (split f16) + score partials ----
  {
    const float kbv[2] = {k_b[dbase + lc], k_b[dbase + 16 + lc]};
    half8 bkh[2][4], bkl[2][4];
#pragma unroll
    for (int dtl = 0; dtl < 2; ++dtl) {
      const int cb = (wave * 2 + dtl) * 4;
#pragma unroll
      for (int ks = 0; ks < 4; ++ks) {
        bkh[dtl][ks] = ld_h8(&wsc[WS_KH + (cb + ks) * 512 + lane * 8]);
        bkl[dtl][ks] = ld_h8(&wsc[WS_KL + (cb + ks) * 512 + lane * 8]);
      }
    }
#pragma unroll
    for (int nt = 0; nt < 4; ++nt) {
      const int row = nt * 16 + lc;
      const int rb  = row * kD;
      const int swz = (row & 7) << 3;
      half8 ah[4];
#pragma unroll
      for (int ks = 0; ks < 4; ++ks)
        ah[ks] = ld_h8(&h3[(rb + ks * 32 + lg * 8) ^ swz]);
      float pr[4] = {0.f, 0.f, 0.f, 0.f};
#pragma unroll
      for (int dtl = 0; dtl < 2; ++dtl) {
        f32x4 aH = {0.f, 0.f, 0.f, 0.f}, aL = {0.f, 0.f, 0.f, 0.f};
#pragma unroll
        for (int ks = 0; ks < 4; ++ks) {
          aH = MFMA16(ah[ks], bkh[dtl][ks], aH);
          aL = MFMA16(ah[ks], bkl[dtl][ks], aL);
        }
#pragma unroll
        for (int r = 0; r < 4; ++r)
          pr[r] = fmaf(qs[dtl], fmaxf(fmaf(kLoInv, aL[r], aH[r]) + kbv[dtl], 0.f), pr[r]);
      }
#pragma unroll
      for (int r = 0; r < 4; ++r) {
        pr[r] += __shfl_xor(pr[r], 1, 64);
        pr[r] += __shfl_xor(pr[r], 2, 64);
        pr[r] += __shfl_xor(pr[r], 4, 64);
        pr[r] += __shfl_xor(pr[r], 8, 64);
      }
      if (lc == 0) {
#pragma unroll
        for (int r = 0; r < 4; ++r) spart[wave][nt * 16 + lg * 4 + r] = pr[r];
      }
    }
  }
  __syncthreads();  // spart ready (t_lds ready since previous barrier)

  // ---- phase D: softmax + output (wave 0 only) ----
  if (wave == 0) {
    const int m = lane;
    float sc = spart[0][m] + spart[1][m] + spart[2][m] + spart[3][m];
    sc = fmaxf(sc * kTemp, 0.f);
    float mx = sc;
#pragma unroll
    for (int off = 32; off > 0; off >>= 1) mx = fmaxf(mx, __shfl_xor(mx, off, 64));
    float e = __expf(sc - mx);
    float s = e;
#pragma unroll
    for (int off = 32; off > 0; off >>= 1) s += __shfl_xor(s, off, 64);
    float val = (e / s) * t_lds[m];
#pragma unroll
    for (int off = 32; off > 0; off >>= 1) val += __shfl_xor(val, off, 64);
    if (lane == 0) {
      const float* fws = (const float*)(wsc + WS_F32);
      float v = val + fws[134];
      const float* s0 = state + (size_t)b * (kN * kF);
#pragma unroll
      for (int j = 0; j < kSelf; ++j) v = fmaf(fws[128 + j], s0[j], v);
      out[b] = v;
    }
  }
}

extern "C" void kernel_launch(void* const* d_in, const int* in_sizes, int n_in,
                              void* d_out, int out_size, void* d_ws, size_t ws_size,
                              hipStream_t stream) {
  const float* state   = (const float*)d_in[0];
  const float* phi1_w  = (const float*)d_in[1];
  const float* phi1_b  = (const float*)d_in[2];
  const float* phi2_w  = (const float*)d_in[3];
  const float* phi2_b  = (const float*)d_in[4];
  const float* phi3_w  = (const float*)d_in[5];
  const float* phi3_b  = (const float*)d_in[6];
  const float* q_w     = (const float*)d_in[7];
  const float* q_b     = (const float*)d_in[8];
  const float* k_w     = (const float*)d_in[9];
  const float* k_b     = (const float*)d_in[10];
  const float* v_w     = (const float*)d_in[11];
  const float* v_b     = (const float*)d_in[12];
  const float* final_w = (const float*)d_in[13];
  const float* final_b = (const float*)d_in[14];
  float* out = (float*)d_out;
  ushort* ws = (ushort*)d_ws;

  prep_kernel<<<dim3(161), dim3(256), 0, stream>>>(
      q_w, k_w, phi3_w, phi2_w, v_w, phi1_w, phi1_b, v_b, final_w, final_b, ws);

  const int batches = in_sizes[0] / (kN * kF);  // 4096
  value_net_kernel<<<dim3(batches), dim3(256), 0, stream>>>(
      state, phi2_b, phi3_b, q_b, k_b, ws, out);
}